// Round 1
// baseline (457.342 us; speedup 1.0000x reference)
//
#include <hip/hip_runtime.h>

// KNN (k=16) within batch-diagonal blocks + neighbor-feature mean-pool.
// N = 16384 points, 8 batches of 2048 (batch ids are arange // 2048,
// contiguous), FEAT = 16.
//
// Correctness strategy: reproduce XLA-CPU's f32 arithmetic bit-for-bit so the
// top-16 selection matches the reference exactly:
//   dot  = fma-chain ascending k (Eigen gemm accumulation order)
//   x2   = rounded squares + sequential adds (elementwise mul then reduce)
//   d2   = (x2 + y2) - 2*dot   (2*dot exact)
//   ties = lower index first (strict '<' everywhere)
// All via __f*_rn intrinsics so hipcc cannot re-contract.

#define KNN_K 16
#define FEAT 16

__global__ __launch_bounds__(64) void knn_mp_kernel(
    const float* __restrict__ x, const float* __restrict__ y,
    const float* __restrict__ feat, const int* __restrict__ x_batch,
    float* __restrict__ out, int n, int per)
{
    // One wave (64 threads) per block; one x-point per thread.
    // Stage this block's batch of y points into LDS as {y0,y1,y2,|y|^2}.
    __shared__ float4 ylds[2048];

    const int i = blockIdx.x * 64 + threadIdx.x;   // query point index
    const int ilim = (i < n) ? i : (n - 1);

    // Batch id is uniform across the block (64 | 2048): read from first point.
    const int b = x_batch[blockIdx.x * 64 < n ? blockIdx.x * 64 : (n - 1)];
    const int ybase = b * per;

    for (int j = (int)threadIdx.x; j < per; j += 64) {
        const float a0 = y[(size_t)(ybase + j) * 3 + 0];
        const float a1 = y[(size_t)(ybase + j) * 3 + 1];
        const float a2 = y[(size_t)(ybase + j) * 3 + 2];
        const float s  = __fadd_rn(__fadd_rn(__fmul_rn(a0, a0),
                                             __fmul_rn(a1, a1)),
                                   __fmul_rn(a2, a2));
        ylds[j] = make_float4(a0, a1, a2, s);
    }
    __syncthreads();

    const float px0 = x[(size_t)ilim * 3 + 0];
    const float px1 = x[(size_t)ilim * 3 + 1];
    const float px2 = x[(size_t)ilim * 3 + 2];
    const float x2s = __fadd_rn(__fadd_rn(__fmul_rn(px0, px0),
                                          __fmul_rn(px1, px1)),
                                __fmul_rn(px2, px2));

    // Sorted ascending (d2, idx) top-K list, registers only (compile-time
    // indexing via full unroll).
    float bd[KNN_K];
    int   bi[KNN_K];
#pragma unroll
    for (int t = 0; t < KNN_K; ++t) { bd[t] = __builtin_inff(); bi[t] = 0; }

    for (int j = 0; j < per; ++j) {
        const float4 q = ylds[j];
        float dot = __fmaf_rn(px0, q.x, 0.0f);
        dot = __fmaf_rn(px1, q.y, dot);
        dot = __fmaf_rn(px2, q.z, dot);
        const float d2 = __fsub_rn(__fadd_rn(x2s, q.w),
                                   __fmul_rn(2.0f, dot));
        // Strict '<': on a tie with the current worst, keep the incumbent
        // (lower index) — matches lax.top_k stable tie-breaking.
        if (d2 < bd[KNN_K - 1]) {
            float cd = d2;
            int   ci = ybase + j;
#pragma unroll
            for (int t = 0; t < KNN_K; ++t) {
                const bool sw = cd < bd[t];
                const float od = bd[t];
                const int   oi = bi[t];
                bd[t] = sw ? cd : od;
                bi[t] = sw ? ci : oi;
                cd = sw ? od : cd;
                ci = sw ? oi : ci;
            }
        }
    }

    if (i < n) {
        // Mean of the K neighbors' features, summed in ascending-rank order
        // (same order as the reference's top_k output), then * 1/16 (exact).
        float acc[FEAT];
#pragma unroll
        for (int f = 0; f < FEAT; ++f) acc[f] = 0.0f;
#pragma unroll
        for (int t = 0; t < KNN_K; ++t) {
            const float* fp = feat + (size_t)bi[t] * FEAT;
#pragma unroll
            for (int f = 0; f < FEAT; ++f)
                acc[f] = __fadd_rn(acc[f], fp[f]);
        }
#pragma unroll
        for (int f = 0; f < FEAT; ++f)
            out[(size_t)i * FEAT + f] = __fmul_rn(acc[f], 0.0625f);
    }
}

extern "C" void kernel_launch(void* const* d_in, const int* in_sizes, int n_in,
                              void* d_out, int out_size, void* d_ws, size_t ws_size,
                              hipStream_t stream) {
    const float* x       = (const float*)d_in[0];
    const float* y       = (const float*)d_in[1];
    const float* feat    = (const float*)d_in[2];
    const int*   x_batch = (const int*)d_in[3];
    // d_in[4] = y_batch (same construction as x_batch; contiguous ranges)

    const int n   = in_sizes[0] / 3;   // 16384
    const int per = n / 8;             // 2048 points per batch (N_BATCHES=8)

    float* out = (float*)d_out;

    const int blocks = (n + 63) / 64;
    knn_mp_kernel<<<blocks, 64, 0, stream>>>(x, y, feat, x_batch, out, n, per);
}

// Round 2
// 269.412 us; speedup vs baseline: 1.6976x; 1.6976x over previous
//
#include <hip/hip_runtime.h>

// KNN (k=16) within batch-diagonal blocks + neighbor-feature mean-pool.
// N = 16384 points, 8 batches of 2048 (contiguous), FEAT = 16.
//
// R1 -> R2: occupancy was 1 wave/CU (2.9%). Split each point's candidate scan
// across NSEG=8 waves (512-thread block): wave w scans candidates
// [w*256, (w+1)*256), keeps a per-lane sorted top-16 in registers, dumps the
// partial lists to LDS, then wave 0 merges 8 sorted lists per point
// (tie-break: lower segment first == lower index first) and gathers features.
//
// Distance arithmetic is bit-identical to R1 (which passed):
//   dot = ascending-k FMA chain; x2/y2 = rounded squares + sequential adds;
//   d2  = (x2 + y2) - 2*dot; strict '<' everywhere for stable ties.

#define KNN_K 16
#define FEAT 16
#define NSEG 8
#define BLK_PTS 64
#define THREADS (NSEG * 64)

__global__ __launch_bounds__(THREADS) void knn_mp_kernel(
    const float* __restrict__ x, const float* __restrict__ y,
    const float* __restrict__ feat, const int* __restrict__ x_batch,
    float* __restrict__ out, int n, int per)
{
    // Stage this block's batch of y points as {y0,y1,y2,|y|^2}.
    __shared__ float4 ylds[2048];
    // Partial top-16 lists: [segment][point][rank]; +1 pad (stride 17) makes
    // the merge phase's per-lane reads (lane stride 17 floats) conflict-free.
    __shared__ float pd[NSEG][BLK_PTS][KNN_K + 1];
    __shared__ int   pi[NSEG][BLK_PTS][KNN_K + 1];

    const int lane  = (int)threadIdx.x & 63;
    const int wv    = (int)threadIdx.x >> 6;     // segment id, 0..7
    const int pbase = blockIdx.x * BLK_PTS;
    const int i     = pbase + lane;              // this lane's query point
    const int ilim  = (i < n) ? i : (n - 1);

    // Batch id is uniform across the block (64 | 2048).
    const int b = x_batch[(pbase < n) ? pbase : (n - 1)];
    const int ybase = b * per;

    // Cooperative y staging (all 512 threads).
    for (int j = (int)threadIdx.x; j < per; j += THREADS) {
        const float a0 = y[(size_t)(ybase + j) * 3 + 0];
        const float a1 = y[(size_t)(ybase + j) * 3 + 1];
        const float a2 = y[(size_t)(ybase + j) * 3 + 2];
        const float s  = __fadd_rn(__fadd_rn(__fmul_rn(a0, a0),
                                             __fmul_rn(a1, a1)),
                                   __fmul_rn(a2, a2));
        ylds[j] = make_float4(a0, a1, a2, s);
    }
    __syncthreads();

    const float px0 = x[(size_t)ilim * 3 + 0];
    const float px1 = x[(size_t)ilim * 3 + 1];
    const float px2 = x[(size_t)ilim * 3 + 2];
    const float x2s = __fadd_rn(__fadd_rn(__fmul_rn(px0, px0),
                                          __fmul_rn(px1, px1)),
                                __fmul_rn(px2, px2));

    // Per-lane sorted top-16 of this wave's segment (registers only).
    float bd[KNN_K];
    int   bi[KNN_K];
#pragma unroll
    for (int t = 0; t < KNN_K; ++t) { bd[t] = __builtin_inff(); bi[t] = 0; }

    const int seg_len = per / NSEG;              // 256
    const int jbeg = wv * seg_len;
    const int jend = jbeg + seg_len;
#pragma unroll 4
    for (int j = jbeg; j < jend; ++j) {
        const float4 q = ylds[j];
        float dot = __fmaf_rn(px0, q.x, 0.0f);
        dot = __fmaf_rn(px1, q.y, dot);
        dot = __fmaf_rn(px2, q.z, dot);
        const float d2 = __fsub_rn(__fadd_rn(x2s, q.w),
                                   __fmul_rn(2.0f, dot));
        if (d2 < bd[KNN_K - 1]) {
            float cd = d2;
            int   ci = ybase + j;
#pragma unroll
            for (int t = 0; t < KNN_K; ++t) {
                const bool sw = cd < bd[t];
                const float od = bd[t];
                const int   oi = bi[t];
                bd[t] = sw ? cd : od;
                bi[t] = sw ? ci : oi;
                cd = sw ? od : cd;
                ci = sw ? oi : ci;
            }
        }
    }

    // Dump partial lists.
#pragma unroll
    for (int t = 0; t < KNN_K; ++t) {
        pd[wv][lane][t] = bd[t];
        pi[wv][lane][t] = bi[t];
    }
    __syncthreads();

    // Wave 0: 8-way merge of sorted lists + feature mean-pool.
    if (threadIdx.x < BLK_PTS && i < n) {
        const int p = lane;
        int h[NSEG];
#pragma unroll
        for (int s = 0; s < NSEG; ++s) h[s] = 0;

        float acc[FEAT];
#pragma unroll
        for (int f = 0; f < FEAT; ++f) acc[f] = 0.0f;

#pragma unroll
        for (int r = 0; r < KNN_K; ++r) {
            float best_d = __builtin_inff();
            int best_s = 0;
#pragma unroll
            for (int s = 0; s < NSEG; ++s) {
                const float d = pd[s][p][h[s]];
                // Strict '<': ties keep the earlier segment (lower index).
                if (d < best_d) { best_d = d; best_s = s; }
            }
            int idx = 0;
#pragma unroll
            for (int s = 0; s < NSEG; ++s)
                if (s == best_s) { idx = pi[s][p][h[s]]; h[s]++; }

            const float* fp = feat + (size_t)idx * FEAT;
#pragma unroll
            for (int f = 0; f < FEAT; ++f)
                acc[f] = __fadd_rn(acc[f], fp[f]);
        }

#pragma unroll
        for (int f = 0; f < FEAT; ++f)
            out[(size_t)i * FEAT + f] = __fmul_rn(acc[f], 0.0625f);
    }
}

extern "C" void kernel_launch(void* const* d_in, const int* in_sizes, int n_in,
                              void* d_out, int out_size, void* d_ws, size_t ws_size,
                              hipStream_t stream) {
    const float* x       = (const float*)d_in[0];
    const float* y       = (const float*)d_in[1];
    const float* feat    = (const float*)d_in[2];
    const int*   x_batch = (const int*)d_in[3];

    const int n   = in_sizes[0] / 3;   // 16384
    const int per = n / 8;             // 2048 per batch

    float* out = (float*)d_out;

    const int blocks = (n + BLK_PTS - 1) / BLK_PTS;
    knn_mp_kernel<<<blocks, THREADS, 0, stream>>>(x, y, feat, x_batch, out, n, per);
}

// Round 3
// 99.220 us; speedup vs baseline: 4.6094x; 2.7153x over previous
//
#include <hip/hip_runtime.h>

// KNN (k=16) within batch-diagonal blocks + neighbor-feature mean-pool.
// N = 16384 points, 8 batches of 2048 (contiguous), FEAT = 16.
//
// R2 -> R3:
//  * 1024-thread blocks (16 waves): wave w scans a 128-candidate segment for
//    the block's 64 points (lane <-> point). 16 waves/CU = 4/SIMD.
//  * No y-LDS staging: prep kernel packs {y0,y1,y2,|y|^2} float4 into d_ws;
//    inner loop reads it with a wave-uniform index (scalar-load path).
//  * Selection via threshold + per-lane 16-slot LDS buffer of packed u64 keys
//    (mono(d2)<<32 | global_idx); wave-collective bitonic sort-16 + merge
//    into a sorted 16-incumbent when any lane's buffer fills. No serial
//    per-candidate insertion chain. u64 key order == (d2 asc, idx asc) ==
//    lax.top_k's stable order, so selection is exact.
//  * Distance arithmetic bit-identical to R1/R2 (which passed):
//    dot = ascending-k FMA chain; y2/x2 = rounded squares + sequential adds;
//    d2 = (x2 + y2) - 2*dot; strict '<' vs threshold.

typedef unsigned long long u64;
typedef unsigned int u32;

#define KNN_K 16
#define FEAT 16
#define NSEG 16                  // waves per block
#define THREADS (NSEG * 64)
#define INF_KEY 0xFFFFFFFFFFFFFFFFull
#define FLUSH_AT 12              // flush when cnt > 12 (checked every 4 iters)

__global__ void knn_prep(const float* __restrict__ y, float4* __restrict__ yp, int m)
{
    const int j = blockIdx.x * 256 + (int)threadIdx.x;
    if (j < m) {
        const float a0 = y[(size_t)j * 3 + 0];
        const float a1 = y[(size_t)j * 3 + 1];
        const float a2 = y[(size_t)j * 3 + 2];
        const float s  = __fadd_rn(__fadd_rn(__fmul_rn(a0, a0), __fmul_rn(a1, a1)),
                                   __fmul_rn(a2, a2));
        yp[j] = make_float4(a0, a1, a2, s);
    }
}

// Swizzled slot within a lane's 16-u64 LDS region: bijection on [0,16) that
// spreads same-logical-slot accesses of the 64 lanes across banks
// (region stride is 128 B = 32 banks; without this, flush reads are 32-way).
__device__ __forceinline__ int sw16(int t, int lane) { return t ^ (lane & 15); }

__device__ __forceinline__ void flush16(u64 (&inc)[16], u64* buf,
                                        int lane, int& cnt, float& thr)
{
    // Read all 16 physical slots (appended entries + INF padding).
    u64 v[16];
#pragma unroll
    for (int t = 0; t < 16; ++t) v[t] = buf[sw16(t, lane)];

    // Bitonic sort, ascending. Fully unrolled -> static reg indexing,
    // wide independent compare-exchanges (no serial chain).
#pragma unroll
    for (int k = 2; k <= 16; k <<= 1) {
#pragma unroll
        for (int j = k >> 1; j > 0; j >>= 1) {
#pragma unroll
            for (int a = 0; a < 16; ++a) {
                const int b = a ^ j;
                if (b > a) {
                    const bool up = (a & k) == 0;
                    const u64 va = v[a], vb = v[b];
                    const bool sw = up ? (vb < va) : (va < vb);
                    v[a] = sw ? vb : va;
                    v[b] = sw ? va : vb;
                }
            }
        }
    }

    // Half-cleaner against sorted incumbent -> lower 16 of the 32 (bitonic).
    u64 m[16];
#pragma unroll
    for (int t = 0; t < 16; ++t) {
        const u64 a = inc[t], b = v[15 - t];
        m[t] = (a < b) ? a : b;
    }
    // Clean the bitonic sequence -> ascending.
#pragma unroll
    for (int j = 8; j > 0; j >>= 1) {
#pragma unroll
        for (int a = 0; a < 16; ++a) {
            const int b = a ^ j;
            if (b > a) {
                const u64 va = m[a], vb = m[b];
                const bool sw = vb < va;
                m[a] = sw ? vb : va;
                m[b] = sw ? va : vb;
            }
        }
    }
#pragma unroll
    for (int t = 0; t < 16; ++t) inc[t] = m[t];

    // Reset buffer to INF.
#pragma unroll
    for (int t = 0; t < 16; ++t) buf[sw16(t, lane)] = INF_KEY;
    cnt = 0;

    // New threshold = d2 of current 16th best (inverse monotonic map).
    const u32 hi   = (u32)(inc[15] >> 32);
    const u32 bits = (hi & 0x80000000u) ? (hi & 0x7FFFFFFFu) : ~hi;
    thr = __uint_as_float(bits);
}

__global__ __launch_bounds__(THREADS, 4) void knn_main(
    const float* __restrict__ x, const float4* __restrict__ yp,
    const float* __restrict__ y, const float* __restrict__ feat,
    const int* __restrict__ x_batch, float* __restrict__ out,
    int n, int per, int packed)
{
    // [segment][point][slot] u64, slot-swizzled. 16*64*16*8 = 128 KiB.
    __shared__ u64 pu[NSEG * 64 * 16];

    const int lane  = (int)threadIdx.x & 63;
    const int wv    = __builtin_amdgcn_readfirstlane((int)(threadIdx.x >> 6));
    const int pbase = blockIdx.x * 64;
    const int i     = pbase + lane;              // this lane's query point

    const int b     = x_batch[pbase];            // uniform across block
    const int ybase = b * per;

    u64* buf = &pu[(wv * 64 + lane) * 16];

    // Prefill buffer with INF (own region; no barrier needed).
#pragma unroll
    for (int t = 0; t < 16; ++t) buf[sw16(t, lane)] = INF_KEY;

    const float px0 = x[(size_t)i * 3 + 0];
    const float px1 = x[(size_t)i * 3 + 1];
    const float px2 = x[(size_t)i * 3 + 2];
    const float x2s = __fadd_rn(__fadd_rn(__fmul_rn(px0, px0), __fmul_rn(px1, px1)),
                                __fmul_rn(px2, px2));

    u64 inc[16];
#pragma unroll
    for (int t = 0; t < 16; ++t) inc[t] = INF_KEY;
    float thr = __builtin_inff();
    int   cnt = 0;

    const int seg_len = per / NSEG;              // 128
    const int jbeg    = ybase + wv * seg_len;    // global y index range

    for (int j4 = 0; j4 < seg_len; j4 += 4) {
#pragma unroll
        for (int u = 0; u < 4; ++u) {
            const int j = jbeg + j4 + u;         // wave-uniform
            float q0, q1, q2, qs;
            if (packed) {
                const float4 q = yp[j];
                q0 = q.x; q1 = q.y; q2 = q.z; qs = q.w;
            } else {
                q0 = y[(size_t)j * 3 + 0];
                q1 = y[(size_t)j * 3 + 1];
                q2 = y[(size_t)j * 3 + 2];
                qs = __fadd_rn(__fadd_rn(__fmul_rn(q0, q0), __fmul_rn(q1, q1)),
                               __fmul_rn(q2, q2));
            }
            float dot = __fmaf_rn(px0, q0, 0.0f);
            dot = __fmaf_rn(px1, q1, dot);
            dot = __fmaf_rn(px2, q2, dot);
            const float d2 = __fsub_rn(__fadd_rn(x2s, qs), __fmul_rn(2.0f, dot));
            if (d2 < thr) {
                // Monotonic f32 -> u32 (handles tiny negative d2 from rounding).
                const u32 bb = __float_as_uint(d2);
                const u32 hi = bb ^ (((u32)(((int)bb) >> 31)) | 0x80000000u);
                buf[sw16(cnt, lane)] = ((u64)hi << 32) | (u32)j;
                cnt++;
            }
        }
        if (__any(cnt > FLUSH_AT)) flush16(inc, buf, lane, cnt, thr);
    }
    if (__any(cnt > 0)) flush16(inc, buf, lane, cnt, thr);

    // Publish this lane's sorted top-16 (reuse buffer region).
#pragma unroll
    for (int t = 0; t < 16; ++t) buf[sw16(t, lane)] = inc[t];
    __syncthreads();

    // 16-way merge + feature gather: 4 points per wave (lanes 0..3).
    if (lane < 4) {
        const int p  = wv * 4 + lane;
        const int ip = pbase + p;

        int h[NSEG];
#pragma unroll
        for (int s = 0; s < NSEG; ++s) h[s] = 0;
        float acc[FEAT];
#pragma unroll
        for (int f = 0; f < FEAT; ++f) acc[f] = 0.0f;

#pragma unroll
        for (int r = 0; r < KNN_K; ++r) {
            u64 best = INF_KEY;
            int bs = 0;
#pragma unroll
            for (int s = 0; s < NSEG; ++s) {
                const u64 d = pu[(s * 64 + p) * 16 + sw16(h[s], p)];
                if (d < best) { best = d; bs = s; }   // keys unique: no ties
            }
#pragma unroll
            for (int s = 0; s < NSEG; ++s)
                if (s == bs) h[s]++;

            const int idx = (int)(u32)best;           // global y index
            const float4* fp = (const float4*)feat + (size_t)idx * 4;
            const float4 f0 = fp[0], f1 = fp[1], f2 = fp[2], f3 = fp[3];
            acc[ 0] = __fadd_rn(acc[ 0], f0.x); acc[ 1] = __fadd_rn(acc[ 1], f0.y);
            acc[ 2] = __fadd_rn(acc[ 2], f0.z); acc[ 3] = __fadd_rn(acc[ 3], f0.w);
            acc[ 4] = __fadd_rn(acc[ 4], f1.x); acc[ 5] = __fadd_rn(acc[ 5], f1.y);
            acc[ 6] = __fadd_rn(acc[ 6], f1.z); acc[ 7] = __fadd_rn(acc[ 7], f1.w);
            acc[ 8] = __fadd_rn(acc[ 8], f2.x); acc[ 9] = __fadd_rn(acc[ 9], f2.y);
            acc[10] = __fadd_rn(acc[10], f2.z); acc[11] = __fadd_rn(acc[11], f2.w);
            acc[12] = __fadd_rn(acc[12], f3.x); acc[13] = __fadd_rn(acc[13], f3.y);
            acc[14] = __fadd_rn(acc[14], f3.z); acc[15] = __fadd_rn(acc[15], f3.w);
        }

        float4* o4 = (float4*)out + (size_t)ip * 4;
#pragma unroll
        for (int c = 0; c < 4; ++c) {
            o4[c] = make_float4(__fmul_rn(acc[c * 4 + 0], 0.0625f),
                                __fmul_rn(acc[c * 4 + 1], 0.0625f),
                                __fmul_rn(acc[c * 4 + 2], 0.0625f),
                                __fmul_rn(acc[c * 4 + 3], 0.0625f));
        }
    }
}

extern "C" void kernel_launch(void* const* d_in, const int* in_sizes, int n_in,
                              void* d_out, int out_size, void* d_ws, size_t ws_size,
                              hipStream_t stream) {
    const float* x       = (const float*)d_in[0];
    const float* y       = (const float*)d_in[1];
    const float* feat    = (const float*)d_in[2];
    const int*   x_batch = (const int*)d_in[3];

    const int n   = in_sizes[0] / 3;   // 16384 query points
    const int m   = in_sizes[1] / 3;   // 16384 y points
    const int per = m / 8;             // 2048 per batch (N_BATCHES = 8)

    float* out = (float*)d_out;

    const size_t need = (size_t)m * sizeof(float4);
    const int packed = (ws_size >= need) ? 1 : 0;
    float4* yp = (float4*)d_ws;

    if (packed)
        knn_prep<<<(m + 255) / 256, 256, 0, stream>>>(y, yp, m);

    const int blocks = n / 64;         // 256
    knn_main<<<blocks, THREADS, 0, stream>>>(x, yp, y, feat, x_batch, out,
                                             n, per, packed);
}

// Round 4
// 78.541 us; speedup vs baseline: 5.8230x; 1.2633x over previous
//
#include <hip/hip_runtime.h>

// KNN (k=16) within batch-diagonal blocks + neighbor-feature mean-pool.
// N = 16384 points, 8 batches of 2048 (contiguous), FEAT = 16.
//
// R3 -> R4:
//  * Shared per-point threshold in LDS (u32 mono-key), tightened by every
//    wave's flush via ds_min_u32, re-read (volatile) each 4-candidate group.
//    Prune only if strictly worse than some wave's 16th-best => exact.
//  * First flush skips the merge-with-incumbent (incumbent is all-INF).
//  * Tail split: index-only 16-way merge (lanes 0..3/wave) -> idx_s, then a
//    full-wave gather: lane=(point,rank), 4x float4 loads, shfl_xor butterfly
//    over ranks. (Feature-sum order differs from reference: rounding-only
//    effect, ~1e-6 << 2.2e-2 threshold. Selection stays bit-exact.)
//  * Distance arithmetic bit-identical to R1-R3 (all passed):
//    dot = ascending-k FMA chain; x2/y2 = rounded squares + sequential adds;
//    d2 = (x2 + y2) - 2*dot.

typedef unsigned long long u64;
typedef unsigned int u32;

#define KNN_K 16
#define FEAT 16
#define NSEG 16                  // waves per block
#define THREADS (NSEG * 64)
#define INF_KEY 0xFFFFFFFFFFFFFFFFull
#define FLUSH_AT 12              // flush when cnt > 12 (checked every 4 iters)
#define THR_INIT 0xFF800000u     // mono-key of +inf

__global__ void knn_prep(const float* __restrict__ y, float4* __restrict__ yp, int m)
{
    const int j = blockIdx.x * 256 + (int)threadIdx.x;
    if (j < m) {
        const float a0 = y[(size_t)j * 3 + 0];
        const float a1 = y[(size_t)j * 3 + 1];
        const float a2 = y[(size_t)j * 3 + 2];
        const float s  = __fadd_rn(__fadd_rn(__fmul_rn(a0, a0), __fmul_rn(a1, a1)),
                                   __fmul_rn(a2, a2));
        yp[j] = make_float4(a0, a1, a2, s);
    }
}

// Swizzled slot within a lane's 16-u64 LDS region (bank spread).
__device__ __forceinline__ int sw16(int t, int lane) { return t ^ (lane & 15); }

// Monotonic f32 -> u32 (order-preserving incl. negatives).
__device__ __forceinline__ u32 mono(float f) {
    const u32 b = __float_as_uint(f);
    return b ^ (((u32)(((int)b) >> 31)) | 0x80000000u);
}
// Inverse of mono().
__device__ __forceinline__ float unmono(u32 h) {
    const u32 b = (h & 0x80000000u) ? (h & 0x7FFFFFFFu) : ~h;
    return __uint_as_float(b);
}

__device__ __forceinline__ void flush16(u64 (&inc)[16], u64* buf, int lane,
                                        int& cnt, bool& first, u32* thr_p)
{
    u64 v[16];
#pragma unroll
    for (int t = 0; t < 16; ++t) v[t] = buf[sw16(t, lane)];

    // Bitonic sort-16, ascending (static indexing, wide independent CEs).
#pragma unroll
    for (int k = 2; k <= 16; k <<= 1) {
#pragma unroll
        for (int j = k >> 1; j > 0; j >>= 1) {
#pragma unroll
            for (int a = 0; a < 16; ++a) {
                const int b = a ^ j;
                if (b > a) {
                    const bool up = (a & k) == 0;
                    const u64 va = v[a], vb = v[b];
                    const bool sw = up ? (vb < va) : (va < vb);
                    v[a] = sw ? vb : va;
                    v[b] = sw ? va : vb;
                }
            }
        }
    }

    if (first) {
#pragma unroll
        for (int t = 0; t < 16; ++t) inc[t] = v[t];
    } else {
        // Half-cleaner vs sorted incumbent -> low 16 (bitonic), then clean.
        u64 m[16];
#pragma unroll
        for (int t = 0; t < 16; ++t) {
            const u64 a = inc[t], b = v[15 - t];
            m[t] = (a < b) ? a : b;
        }
#pragma unroll
        for (int j = 8; j > 0; j >>= 1) {
#pragma unroll
            for (int a = 0; a < 16; ++a) {
                const int b = a ^ j;
                if (b > a) {
                    const u64 va = m[a], vb = m[b];
                    const bool sw = vb < va;
                    m[a] = sw ? vb : va;
                    m[b] = sw ? va : vb;
                }
            }
        }
#pragma unroll
        for (int t = 0; t < 16; ++t) inc[t] = m[t];
    }
    first = false;

#pragma unroll
    for (int t = 0; t < 16; ++t) buf[sw16(t, lane)] = INF_KEY;
    cnt = 0;

    // Tighten the shared per-point threshold (monotone decreasing; racy
    // staleness only loses pruning efficiency, never correctness).
    atomicMin(thr_p, (u32)(inc[15] >> 32));
}

__global__ __launch_bounds__(THREADS, 4) void knn_main(
    const float* __restrict__ x, const float4* __restrict__ yp,
    const float* __restrict__ y, const float* __restrict__ feat,
    const int* __restrict__ x_batch, float* __restrict__ out,
    int n, int per, int packed)
{
    __shared__ u64 pu[NSEG * 64 * 16];     // 128 KiB candidate/partial lists
    __shared__ u32 idx_s[64 * KNN_K];      // 4 KiB winning indices
    __shared__ u32 thr_s[64];              // shared per-point thresholds

    const int lane  = (int)threadIdx.x & 63;
    const int wv    = __builtin_amdgcn_readfirstlane((int)(threadIdx.x >> 6));
    const int pbase = blockIdx.x * 64;

    const int b     = x_batch[pbase];      // uniform across block
    const int ybase = b * per;

    u64* buf = &pu[(wv * 64 + lane) * 16];
#pragma unroll
    for (int t = 0; t < 16; ++t) buf[sw16(t, lane)] = INF_KEY;
    if (threadIdx.x < 64) thr_s[threadIdx.x] = THR_INIT;
    __syncthreads();

    const int i = pbase + lane;            // this lane's query point
    const float px0 = x[(size_t)i * 3 + 0];
    const float px1 = x[(size_t)i * 3 + 1];
    const float px2 = x[(size_t)i * 3 + 2];
    const float x2s = __fadd_rn(__fadd_rn(__fmul_rn(px0, px0), __fmul_rn(px1, px1)),
                                __fmul_rn(px2, px2));

    u64 inc[16];
#pragma unroll
    for (int t = 0; t < 16; ++t) inc[t] = INF_KEY;
    bool first = true;
    int  cnt   = 0;
    u32* thr_p = &thr_s[lane];

    const int seg_len = per / NSEG;        // 128
    const int jbeg    = ybase + wv * seg_len;

    for (int j4 = 0; j4 < seg_len; j4 += 4) {
        // Stale-tolerant read of the shared threshold (float domain so the
        // per-candidate compare is 1 op). Keep iff d2 <= thr (tie-safe).
        const u32  thr_u = *(volatile u32*)thr_p;
        const float thrf = unmono(thr_u);
#pragma unroll
        for (int u = 0; u < 4; ++u) {
            const int j = jbeg + j4 + u;   // wave-uniform
            float q0, q1, q2, qs;
            if (packed) {
                const float4 q = yp[j];
                q0 = q.x; q1 = q.y; q2 = q.z; qs = q.w;
            } else {
                q0 = y[(size_t)j * 3 + 0];
                q1 = y[(size_t)j * 3 + 1];
                q2 = y[(size_t)j * 3 + 2];
                qs = __fadd_rn(__fadd_rn(__fmul_rn(q0, q0), __fmul_rn(q1, q1)),
                               __fmul_rn(q2, q2));
            }
            float dot = __fmaf_rn(px0, q0, 0.0f);
            dot = __fmaf_rn(px1, q1, dot);
            dot = __fmaf_rn(px2, q2, dot);
            const float d2 = __fsub_rn(__fadd_rn(x2s, qs), __fmul_rn(2.0f, dot));
            if (d2 <= thrf) {
                buf[sw16(cnt, lane)] = ((u64)mono(d2) << 32) | (u32)j;
                cnt++;
            }
        }
        if (__any(cnt > FLUSH_AT)) flush16(inc, buf, lane, cnt, first, thr_p);
    }
    if (__any(cnt > 0)) flush16(inc, buf, lane, cnt, first, thr_p);

    // Publish sorted per-segment top-16 (reuse buffer region).
#pragma unroll
    for (int t = 0; t < 16; ++t) buf[sw16(t, lane)] = inc[t];
    __syncthreads();

    // Index-only 16-way merge: lanes 0..3, point p = wv*4 + lane.
    if (lane < 4) {
        const int p = wv * 4 + lane;
        int h[NSEG];
#pragma unroll
        for (int s = 0; s < NSEG; ++s) h[s] = 0;
#pragma unroll
        for (int r = 0; r < KNN_K; ++r) {
            u64 best = INF_KEY;
            int bs = 0;
#pragma unroll
            for (int s = 0; s < NSEG; ++s) {
                const u64 d = pu[(s * 64 + p) * 16 + sw16(h[s], p)];
                if (d < best) { best = d; bs = s; }   // keys unique
            }
#pragma unroll
            for (int s = 0; s < NSEG; ++s)
                if (s == bs) h[s]++;
            idx_s[p * KNN_K + r] = (u32)best;         // low word = y index
        }
    }
    // Same-wave producer/consumer (no __syncthreads needed: in-order DS pipe,
    // and the shared-array dependence stops compiler reordering).

    // Full-wave gather: lane = (point gp, rank gr); butterfly-sum over ranks.
    const int gp = lane >> 4;              // 0..3 (point within wave's quad)
    const int gr = lane & 15;              // rank
    const int p_out = wv * 4 + gp;
    const int gidx = (int)idx_s[p_out * KNN_K + gr];

    const float4* fp = (const float4*)feat + (size_t)gidx * 4;
    const float4 f0 = fp[0], f1 = fp[1], f2 = fp[2], f3 = fp[3];
    float f[FEAT] = { f0.x, f0.y, f0.z, f0.w, f1.x, f1.y, f1.z, f1.w,
                      f2.x, f2.y, f2.z, f2.w, f3.x, f3.y, f3.z, f3.w };
#pragma unroll
    for (int mask = 1; mask <= 8; mask <<= 1) {
#pragma unroll
        for (int c = 0; c < FEAT; ++c)
            f[c] = __fadd_rn(f[c], __shfl_xor(f[c], mask));
    }
    if (gr < 4) {
        float4* o4 = (float4*)out + (size_t)(pbase + p_out) * 4;
        o4[gr] = make_float4(__fmul_rn(f[gr * 4 + 0], 0.0625f),
                             __fmul_rn(f[gr * 4 + 1], 0.0625f),
                             __fmul_rn(f[gr * 4 + 2], 0.0625f),
                             __fmul_rn(f[gr * 4 + 3], 0.0625f));
    }
}

extern "C" void kernel_launch(void* const* d_in, const int* in_sizes, int n_in,
                              void* d_out, int out_size, void* d_ws, size_t ws_size,
                              hipStream_t stream) {
    const float* x       = (const float*)d_in[0];
    const float* y       = (const float*)d_in[1];
    const float* feat    = (const float*)d_in[2];
    const int*   x_batch = (const int*)d_in[3];

    const int n   = in_sizes[0] / 3;   // 16384 query points
    const int m   = in_sizes[1] / 3;   // 16384 y points
    const int per = m / 8;             // 2048 per batch (N_BATCHES = 8)

    float* out = (float*)d_out;

    const size_t need = (size_t)m * sizeof(float4);
    const int packed = (ws_size >= need) ? 1 : 0;
    float4* yp = (float4*)d_ws;

    if (packed)
        knn_prep<<<(m + 255) / 256, 256, 0, stream>>>(y, yp, m);

    const int blocks = n / 64;         // 256
    knn_main<<<blocks, THREADS, 0, stream>>>(x, yp, y, feat, x_batch, out,
                                             n, per, packed);
}